// Round 1
// baseline (18363.820 us; speedup 1.0000x reference)
//
#include <hip/hip_runtime.h>
#include <cmath>

// Problem constants (setup_inputs): B=64, S=1024, I=1024, H=1024, fp32.
constexpr int B = 64, S = 1024, I = 1024, H = 1024;
constexpr int KSPLIT = 16;            // fallback path only

// ---------------------------------------------------------------------------
// Phase 1: wx[m,n] = sum_k x[m,k] * Wih_w[n,k] + Wih_b[n]   (unchanged)
// ---------------------------------------------------------------------------
__global__ __launch_bounds__(256) void gemm_nt(
    const float* __restrict__ A, const float* __restrict__ W,
    const float* __restrict__ bias, float* __restrict__ C) {
  __shared__ float As[16][68];   // [k][m], +4 pad keeps float4 alignment
  __shared__ float Bs[16][68];   // [k][n]
  const int tid = threadIdx.x;
  const int m0 = blockIdx.y * 64;
  const int n0 = blockIdx.x * 64;
  const int tx = tid & 15;        // n-thread
  const int ty = tid >> 4;        // m-thread
  const int lr = tid >> 2;        // 0..63 staging row
  const int lc = (tid & 3) * 4;   // 0,4,8,12 staging col (k)

  const float* Ap = A + (size_t)(m0 + lr) * I + lc;
  const float* Wp = W + (size_t)(n0 + lr) * I + lc;

  float acc[4][4] = {};
  for (int k0 = 0; k0 < I; k0 += 16) {
    float4 av = *(const float4*)(Ap + k0);
    float4 wv = *(const float4*)(Wp + k0);
    As[lc + 0][lr] = av.x; As[lc + 1][lr] = av.y;
    As[lc + 2][lr] = av.z; As[lc + 3][lr] = av.w;
    Bs[lc + 0][lr] = wv.x; Bs[lc + 1][lr] = wv.y;
    Bs[lc + 2][lr] = wv.z; Bs[lc + 3][lr] = wv.w;
    __syncthreads();
#pragma unroll
    for (int kk = 0; kk < 16; ++kk) {
      float4 a = *(const float4*)&As[kk][ty * 4];
      float4 b = *(const float4*)&Bs[kk][tx * 4];
      float ar[4] = {a.x, a.y, a.z, a.w};
      float br[4] = {b.x, b.y, b.z, b.w};
#pragma unroll
      for (int i = 0; i < 4; ++i)
#pragma unroll
        for (int j = 0; j < 4; ++j) acc[i][j] += ar[i] * br[j];
    }
    __syncthreads();
  }
  float bj[4];
#pragma unroll
  for (int j = 0; j < 4; ++j) bj[j] = bias[n0 + tx * 4 + j];
#pragma unroll
  for (int i = 0; i < 4; ++i) {
    int m = m0 + ty * 4 + i;
    float4 o = make_float4(acc[i][0] + bj[0], acc[i][1] + bj[1],
                           acc[i][2] + bj[2], acc[i][3] + bj[3]);
    *(float4*)&C[(size_t)m * H + n0 + tx * 4] = o;
  }
}

// ---------------------------------------------------------------------------
// Phase 2: persistent cooperative scan. One launch for all S steps.
//
// 256 blocks (= 1/CU) x 1024 threads (16 waves, 4/SIMD).
// Block (bg,gg) owns output tile b in [bg*16,+16), g in [gg*16,+16).
// Whh rows g0..g0+15 (64 KB) staged in LDS ONCE -- zero per-step W traffic,
// immune to the L2 invalidation the inter-step fence performs.
// Per step: stage h tile (64 KB) -> 256 dots of length 1024 (4-way K-split
// across thread groups, LDS-reduced) -> tanh + in-place y write -> grid
// barrier (4 spread monotonic counters + agent-scope release/acquire).
// ---------------------------------------------------------------------------
constexpr int SCAN_BLOCKS  = 256;
constexpr int SCAN_THREADS = 1024;
constexpr int LP = 1028;                         // LDS pitch: 1024+4 floats
                                                 //  -> 16B-aligned rows, 2-way
                                                 //     max bank aliasing (free)
constexpr int SMEM_FLOATS = 2 * 16 * LP + 3 * 256;   // Ws + Hs + red
constexpr size_t SMEM_BYTES = (size_t)SMEM_FLOATS * sizeof(float);  // ~131.5 KB

__global__ __launch_bounds__(SCAN_THREADS) void rnn_scan(
    const float* __restrict__ h0, const float* __restrict__ Whh,
    const float* __restrict__ bias, float* __restrict__ y,
    float* __restrict__ hlast, unsigned* __restrict__ bar) {
  extern __shared__ float smem[];
  float* Ws  = smem;                 // [16][LP] : Whh rows g0..g0+15
  float* Hs  = smem + 16 * LP;       // [16][LP] : h rows b0..b0+15
  float* red = smem + 32 * LP;       // [3][256] : K-split partial sums

  const int tid = threadIdx.x;
  const int blk = blockIdx.x;
  const int g0 = (blk & 63) * 16;
  const int b0 = (blk >> 6) * 16;
  const int out = tid & 255;         // output id within tile
  const int tx  = out & 15;          // g offset
  const int ty  = out >> 4;          // b offset
  const int kq  = tid >> 8;          // 0..3 K-quarter
  const int kbase = kq * 256;

  // ---- stage Whh tile once (rows g0..g0+15, 4096 float4s) ----
#pragma unroll
  for (int p = 0; p < 4; ++p) {
    const int fidx = p * SCAN_THREADS + tid;     // 0..4095
    const int r = fidx >> 8;                     // row 0..15
    const int c = (fidx & 255) * 4;              // col 0..1020
    const float4 v = *(const float4*)(Whh + (size_t)(g0 + r) * H + c);
    *(float4*)&Ws[r * LP + c] = v;
  }
  const float bj = bias[g0 + tx];
  const float* hrow = &Hs[ty * LP + kbase];
  const float* wrow = &Ws[tx * LP + kbase];

  for (int t = 0; t < S; ++t) {
    // ---- stage h tile: rows b0..b0+15 of h_{t-1} ----
    const float* hp = (t == 0) ? (h0 + (size_t)b0 * H)
                               : (y + ((size_t)b0 * S + (t - 1)) * H);
    const size_t hstr = (t == 0) ? (size_t)H : (size_t)S * H;
#pragma unroll
    for (int p = 0; p < 4; ++p) {
      const int fidx = p * SCAN_THREADS + tid;
      const int r = fidx >> 8;
      const int c = (fidx & 255) * 4;
      const float4 v = *(const float4*)(hp + (size_t)r * hstr + c);
      *(float4*)&Hs[r * LP + c] = v;
    }
    // prefetch wx for our own output element (tile owned by this block only)
    float* yp = &y[((size_t)(b0 + ty) * S + t) * H + g0 + tx];
    const float wx = (kq == 0) ? *yp : 0.f;
    __syncthreads();

    // ---- quarter-dot: 256 MACs/thread, 4 independent accumulators ----
    float a0 = 0.f, a1 = 0.f, a2 = 0.f, a3 = 0.f;
#pragma unroll
    for (int k = 0; k < 256; k += 16) {
      float4 h0v = *(const float4*)(hrow + k + 0);
      float4 w0v = *(const float4*)(wrow + k + 0);
      float4 h1v = *(const float4*)(hrow + k + 4);
      float4 w1v = *(const float4*)(wrow + k + 4);
      float4 h2v = *(const float4*)(hrow + k + 8);
      float4 w2v = *(const float4*)(wrow + k + 8);
      float4 h3v = *(const float4*)(hrow + k + 12);
      float4 w3v = *(const float4*)(wrow + k + 12);
      a0 = fmaf(h0v.x, w0v.x, a0); a0 = fmaf(h0v.y, w0v.y, a0);
      a0 = fmaf(h0v.z, w0v.z, a0); a0 = fmaf(h0v.w, w0v.w, a0);
      a1 = fmaf(h1v.x, w1v.x, a1); a1 = fmaf(h1v.y, w1v.y, a1);
      a1 = fmaf(h1v.z, w1v.z, a1); a1 = fmaf(h1v.w, w1v.w, a1);
      a2 = fmaf(h2v.x, w2v.x, a2); a2 = fmaf(h2v.y, w2v.y, a2);
      a2 = fmaf(h2v.z, w2v.z, a2); a2 = fmaf(h2v.w, w2v.w, a2);
      a3 = fmaf(h3v.x, w3v.x, a3); a3 = fmaf(h3v.y, w3v.y, a3);
      a3 = fmaf(h3v.z, w3v.z, a3); a3 = fmaf(h3v.w, w3v.w, a3);
    }
    float acc = (a0 + a1) + (a2 + a3);
    if (kq != 0) red[(kq - 1) * 256 + out] = acc;
    __syncthreads();
    if (kq == 0) {
      acc += red[out] + red[256 + out] + red[512 + out];
      const float v = tanhf(wx + bj + acc);
      *yp = v;
      if (t == S - 1) hlast[(size_t)(b0 + ty) * H + g0 + tx] = v;
    }

    // ---- grid barrier (skip after last step) ----
    if (t != S - 1) {
      // All threads: drain own global stores to L2 (compiler-ordered fence,
      // no cache maintenance at workgroup scope).
      __builtin_amdgcn_fence(__ATOMIC_RELEASE, "workgroup");
      __syncthreads();
      if (tid == 0) {
        // One L2 writeback per block, then arrive.
        __builtin_amdgcn_fence(__ATOMIC_RELEASE, "agent");
        __hip_atomic_fetch_add(&bar[(blk & 3) * 64], 1u, __ATOMIC_RELAXED,
                               __HIP_MEMORY_SCOPE_AGENT);
        const unsigned tgt = (unsigned)(t + 1) * 64u;   // 64 arrivals/counter
#pragma unroll 1
        for (int c = 0; c < 4; ++c)
          while (__hip_atomic_load(&bar[c * 64], __ATOMIC_RELAXED,
                                   __HIP_MEMORY_SCOPE_AGENT) < tgt) { }
        // One L2/L1 invalidate per block; later loads (after s_barrier) miss
        // to L3 and see every other XCD's step-t writes.
        __builtin_amdgcn_fence(__ATOMIC_ACQUIRE, "agent");
      }
      __syncthreads();
    }
  }
}

// ---------------------------------------------------------------------------
// Fallback path (previous verified kernels) -- used only if cooperative
// launch is rejected.
// ---------------------------------------------------------------------------
__global__ __launch_bounds__(256) void rnn_step_gemm(
    const float* __restrict__ hprev, long hstride,
    const float* __restrict__ W, float* __restrict__ partial) {
  __shared__ float Wsm[64][68];
  __shared__ float Hsm[64][68];
  const int tid = threadIdx.x;
  const int g0 = blockIdx.x * 64;
  const int k0 = blockIdx.y * 64;
  const int tx = tid & 15;
  const int ty = tid >> 4;
  {
    const int r = tid >> 4;
    const int c = (tid & 15) * 4;
#pragma unroll
    for (int p = 0; p < 4; ++p) {
      const int rr = r + p * 16;
      float4 wv = *(const float4*)(W + (size_t)(g0 + rr) * H + k0 + c);
      float4 hv = *(const float4*)(hprev + (size_t)rr * hstride + k0 + c);
      Wsm[c + 0][rr] = wv.x; Wsm[c + 1][rr] = wv.y;
      Wsm[c + 2][rr] = wv.z; Wsm[c + 3][rr] = wv.w;
      Hsm[c + 0][rr] = hv.x; Hsm[c + 1][rr] = hv.y;
      Hsm[c + 2][rr] = hv.z; Hsm[c + 3][rr] = hv.w;
    }
  }
  __syncthreads();
  float acc[4][4] = {};
#pragma unroll 16
  for (int kk = 0; kk < 64; ++kk) {
    float4 hb = *(const float4*)&Hsm[kk][ty * 4];
    float4 wb = *(const float4*)&Wsm[kk][tx * 4];
    float hr[4] = {hb.x, hb.y, hb.z, hb.w};
    float wr[4] = {wb.x, wb.y, wb.z, wb.w};
#pragma unroll
    for (int i = 0; i < 4; ++i)
#pragma unroll
      for (int j = 0; j < 4; ++j) acc[i][j] += hr[i] * wr[j];
  }
#pragma unroll
  for (int i = 0; i < 4; ++i) {
    const int b = ty * 4 + i;
    float4 o = make_float4(acc[i][0], acc[i][1], acc[i][2], acc[i][3]);
    *(float4*)&partial[((size_t)blockIdx.y * B + b) * H + g0 + tx * 4] = o;
  }
}

__global__ __launch_bounds__(256) void rnn_finalize(
    const float* __restrict__ partial, const float* __restrict__ bias,
    float* __restrict__ yx, long ystride, float* __restrict__ hlast) {
  const int idx = blockIdx.x * 256 + threadIdx.x;
  const int b = idx >> 10;
  const int g = idx & 1023;
  float v = yx[(size_t)b * ystride + g] + bias[g];
#pragma unroll
  for (int ks = 0; ks < KSPLIT; ++ks)
    v += partial[((size_t)ks * B + b) * H + g];
  v = tanhf(v);
  yx[(size_t)b * ystride + g] = v;
  if (hlast) hlast[idx] = v;
}

// ---------------------------------------------------------------------------
extern "C" void kernel_launch(void* const* d_in, const int* in_sizes, int n_in,
                              void* d_out, int out_size, void* d_ws, size_t ws_size,
                              hipStream_t stream) {
  const float* x     = (const float*)d_in[0];  // [B,S,I]
  const float* h0    = (const float*)d_in[1];  // [B,H]
  const float* Wih_w = (const float*)d_in[2];  // [H,I]
  const float* Wih_b = (const float*)d_in[3];  // [H]
  const float* Whh_w = (const float*)d_in[4];  // [H,H]
  const float* Whh_b = (const float*)d_in[5];  // [H]

  float* y     = (float*)d_out;                // [B,S,H]
  float* hlast = y + (size_t)B * S * H;        // [B,H]
  unsigned* bar = (unsigned*)d_ws;             // 4 counters, 256 B apart

  // Barrier counters must start at 0 on every (graph-replayed) run.
  hipMemsetAsync(bar, 0, 4 * 64 * sizeof(unsigned), stream);

  // Phase 1: wx -> y region. M = B*S = 65536 rows.
  gemm_nt<<<dim3(H / 64, (B * S) / 64), 256, 0, stream>>>(x, Wih_w, Wih_b, y);

  static bool attr_done = false;
  if (!attr_done) {
    hipFuncSetAttribute((const void*)rnn_scan,
                        hipFuncAttributeMaxDynamicSharedMemorySize,
                        (int)SMEM_BYTES);
    attr_done = true;
  }

  const float* a_h0 = h0; const float* a_W = Whh_w; const float* a_b = Whh_b;
  float* a_y = y; float* a_hl = hlast; unsigned* a_bar = bar;
  void* args[] = {&a_h0, &a_W, &a_b, &a_y, &a_hl, &a_bar};
  hipError_t ce = hipLaunchCooperativeKernel(
      (const void*)rnn_scan, dim3(SCAN_BLOCKS), dim3(SCAN_THREADS), args,
      (unsigned)SMEM_BYTES, stream);

  if (ce != hipSuccess) {
    // Fallback: previous verified per-step launch path.
    float* partial = (float*)d_ws + 256;   // past the barrier region
    for (int t = 0; t < S; ++t) {
      const float* hprev = (t == 0) ? h0 : (y + (size_t)(t - 1) * H);
      const long hstride = (t == 0) ? (long)H : (long)S * H;
      rnn_step_gemm<<<dim3(H / 64, KSPLIT), 256, 0, stream>>>(
          hprev, hstride, Whh_w, partial);
      rnn_finalize<<<256, 256, 0, stream>>>(
          partial, Whh_b, y + (size_t)t * H, (long)S * H,
          (t == S - 1) ? hlast : nullptr);
    }
  }
}